// Round 14
// baseline (176.135 us; speedup 1.0000x reference)
//
#include <hip/hip_runtime.h>
#include <hip/hip_bf16.h>
#include <math.h>

// B=2, S=2048, D=1024, H=16, dk=64.
// wsplit4 -> ONE fused tri-GEMM (q/k/v projections; A staged RAW FP32 via
// global_load_lds, hi/lo split in-register with v_cvt_pk_bf16_f32; 32x32x16
// MFMA; fused RoPE / tiled-V epilogues) -> 32x32-MFMA flash attention
// (8-wave, KVBLK=128, register softmax, permlane32_swap) -> 32x32 split-GEMM.
//
// GEMM wave grid 4(wr: 32-row bands) x 2(wc: 64-col bands); per wave 2 n-frags
// of 32x32, acc = 2 x f32x16. C/D map: col=lane&31, row=(reg&3)+8*(reg>>2)+4*hi.
//
// trigemm LDS per buf (32KB x 2): A fp32 tile 16KB | Wh 8KB | Wl 8KB.
//  A tile: 128 rows x 32 fp32; 16B chunk (R,c), c=0..7: linear u = R*8 + (c^(R&7)).
//  W tiles: [128][32] bf16, u16-offset swz(R,c) (superrow XOR).
// All staging via global_load_lds: linear dest + pre-permuted per-lane source.
//
// Tiled K layout per (b,h): 64-key tile t at t*4096 elems; within tile:
//   elem(key r, dk d) at chunk(d>>3)*512 + r*8 + (d&7).
// Tiled V layout per (b,h): 64-key tile t at t*4096; elem(dk dkr, key s):
//   chunk((s&63)>>3)*512 + dkr*8 + (s&7).
//
// ws (64 MB):
//  [0,8) Xh  [8,16) Xl | [16,24) qb | [24,32) vt | [40,48) kb | [48,64) W splits

#define B_ 2
#define S_ 2048
#define D_ 1024
#define H_ 16
#define DK 64

typedef __attribute__((ext_vector_type(8)))  __bf16 bf16x8;
typedef __attribute__((ext_vector_type(4)))  float  f32x4;
typedef __attribute__((ext_vector_type(16))) float  f32x16;
typedef __attribute__((ext_vector_type(8)))  unsigned short u16x8;
typedef __attribute__((ext_vector_type(4)))  unsigned short u16x4;

#if __has_builtin(__builtin_amdgcn_exp2f)
#define EXP2(x) __builtin_amdgcn_exp2f(x)
#else
#define EXP2(x) exp2f(x)
#endif

static __device__ __forceinline__ unsigned short f2bf(float x) {
    union { float f; unsigned u; } v; v.f = x;
    unsigned r = v.u + 0x7FFFu + ((v.u >> 16) & 1u);   // RNE
    return (unsigned short)(r >> 16);
}
static __device__ __forceinline__ float bf2f(unsigned short h) {
    union { unsigned u; float f; } v; v.u = ((unsigned)h) << 16;
    return v.f;
}
static __device__ __forceinline__ unsigned cvtpk(float lo, float hi) {
    unsigned r;
    asm("v_cvt_pk_bf16_f32 %0, %1, %2" : "=v"(r) : "v"(lo), "v"(hi));
    return r;
}
static __device__ __forceinline__ void gload_lds16(const void* g, void* l) {
    __builtin_amdgcn_global_load_lds(
        (const __attribute__((address_space(1))) void*)g,
        (__attribute__((address_space(3))) void*)l, 16, 0, 0);
}
// shorts offset of logical (row R, 8-elem chunk c) in an 8KB [128][32]bf16 tile.
static __device__ __forceinline__ int swz(int R, int c) {
    return ((R >> 1) << 6) + (((((R & 1) << 2) | c) ^ ((R >> 1) & 7)) << 3);
}
union bfrag { unsigned u[4]; bf16x8 v; };
// split 2 fp32 -> one hi dword + one lo dword (bf16 pairs), RNE, self-correcting.
static __device__ __forceinline__ void splitpk(float e0, float e1,
                                               unsigned& hd, unsigned& ld) {
    hd = cvtpk(e0, e1);
    union { unsigned u; float f; } flo, fhi;
    flo.u = hd << 16; fhi.u = hd & 0xFFFF0000u;
    ld = cvtpk(e0 - flo.f, e1 - fhi.f);
}

// ---------------------------------------------------------------------------
// 4-weight fp32 -> bf16 hi/lo split (cvtpk). per weight t: hi @ t*2M, lo @ +1M.
// ---------------------------------------------------------------------------
__global__ __launch_bounds__(256) void wsplit4(
    const float* __restrict__ W0, const float* __restrict__ W1,
    const float* __restrict__ W2, const float* __restrict__ W3,
    unsigned short* __restrict__ out)
{
    const int idx = blockIdx.x * 256 + threadIdx.x;
    const int t = idx >> 17;
    const size_t e = (size_t)(idx & 131071) * 8;
    const float* src = (t==0 ? W0 : t==1 ? W1 : t==2 ? W2 : W3) + e;
    unsigned short* hi = out + (size_t)t * 2097152 + e;
    unsigned short* lo = hi + 1048576;
    float4 a = *(const float4*)src;
    float4 b = *(const float4*)(src + 4);
    float x[8] = {a.x,a.y,a.z,a.w,b.x,b.y,b.z,b.w};
    union { unsigned u[4]; u16x8 v; } H, L;
    #pragma unroll
    for (int j = 0; j < 4; ++j) splitpk(x[2*j], x[2*j+1], H.u[j], L.u[j]);
    *(u16x8*)hi = H.v;
    *(u16x8*)lo = L.v;
}

// ---------------------------------------------------------------------------
// Fused tri-GEMM (blockIdx.z = problem), 32x32x16 MFMA. A staged fp32 via
// global_load_lds (waves 0-3); W hi/lo via global_load_lds (waves 4-7).
// A split to bf16 hi/lo in-register (cvtpk). One barrier per K-step.
// pid 0: RoPE*QSC -> qb (B,H,S,dk). pid 1: RoPE -> kb TILED. pid 2: vt TILED.
// ---------------------------------------------------------------------------
__global__ __launch_bounds__(512) void trigemm(
    const float* __restrict__ Aq, const float* __restrict__ Ak,
    const float* __restrict__ Av, const unsigned short* __restrict__ wsp,
    const float* __restrict__ bq, const float* __restrict__ bk,
    const float* __restrict__ bv,
    unsigned short* __restrict__ qb, unsigned short* __restrict__ kb,
    unsigned short* __restrict__ vt)
{
    __shared__ __align__(16) char ldsb[65536];   // 2 bufs x (A 16K | Wh 8K | Wl 8K)
    const int pid = blockIdx.z;
    const float* A    = (pid==0) ? Aq : (pid==1) ? Ak : Av;
    const float* bias = (pid==0) ? bq : (pid==1) ? bk : bv;

    const int tid = threadIdx.x;
    const int w = tid >> 6, lane = tid & 63;
    const int l31 = lane & 31, hi = lane >> 5;
    const int wr = w >> 1, wc = w & 1;           // 4 x 2 wave grid
    const int bx = blockIdx.x, by = blockIdx.y;

    // ---- staging geometry (per-lane permuted sources, linear LDS dests) ----
    const int lr8 = lane >> 3;               // 0..7
    const int zz  = (lane & 7) ^ lr8;        // permuted slot
    // A (waves 0-3): lane covers row w*32 + j*8 + lr8, fp32 chunk zz (16B)
    const float* gpA = A + (size_t)(bx*128 + w*32 + lr8) * 1024 + zz * 4;
    // W (waves 4-7): p = w-4; tensor tp = p>>1 (0=Wh,1=Wl); q = p&1
    const int p_ = w - 4, tp = (p_ >> 1) & 1, qq = p_ & 1;
    const unsigned short* Wbase = wsp + (size_t)pid * 2097152 + (size_t)tp * 1048576;
    const int wR0 = qq*64 + (lr8 << 1) + (zz >> 2);
    const unsigned short* gpW = Wbase + (size_t)(by*128 + wR0) * 1024 + (zz & 3) * 8;

    f32x16 acc[2];
    #pragma unroll
    for (int n = 0; n < 2; ++n)
        #pragma unroll
        for (int r = 0; r < 16; ++r) acc[n][r] = 0.f;

    #define STAGE(T, BUF) do {                                               \
        if (w < 4) {                                                         \
            const float* g_ = gpA + (size_t)(T) * 32;                        \
            char* d_ = ldsb + (BUF)*32768 + w*4096;                          \
            gload_lds16(g_,          d_);                                    \
            gload_lds16(g_ + 8192,   d_ + 1024);                             \
            gload_lds16(g_ + 16384,  d_ + 2048);                             \
            gload_lds16(g_ + 24576,  d_ + 3072);                             \
        } else {                                                             \
            const unsigned short* g_ = gpW + (size_t)(T) * 32;               \
            char* d_ = ldsb + (BUF)*32768 + 16384 + tp*8192 + qq*4096;       \
            gload_lds16(g_,          d_);                                    \
            gload_lds16(g_ + 16384,  d_ + 1024);                             \
            gload_lds16(g_ + 32768,  d_ + 2048);                             \
            gload_lds16(g_ + 49152,  d_ + 3072);                             \
        }                                                                    \
    } while (0)

    STAGE(0, 0);
    __syncthreads();

    for (int t = 0; t < 32; ++t) {
        const int cur = t & 1;
        if (t < 31) STAGE(t + 1, cur ^ 1);
        const char* Abuf = ldsb + cur * 32768;
        const unsigned short* Whb = (const unsigned short*)(Abuf + 16384);
        const unsigned short* Wlb = Whb + 4096;

        // ---- A frags (fp32 -> in-register hi/lo split); row = wr*32 + l31 ----
        const int R = wr*32 + l31;
        const int b8 = R * 8, r7 = R & 7;
        bfrag ah[2], al[2];
        #pragma unroll
        for (int kh = 0; kh < 2; ++kh) {
            const int c0 = kh*4 + hi*2;
            f32x4 x0 = *(const f32x4*)(Abuf + (size_t)(b8 + (c0       ^ r7)) * 16);
            f32x4 x1 = *(const f32x4*)(Abuf + (size_t)(b8 + ((c0 + 1) ^ r7)) * 16);
            splitpk(x0[0], x0[1], ah[kh].u[0], al[kh].u[0]);
            splitpk(x0[2], x0[3], ah[kh].u[1], al[kh].u[1]);
            splitpk(x1[0], x1[1], ah[kh].u[2], al[kh].u[2]);
            splitpk(x1[2], x1[3], ah[kh].u[3], al[kh].u[3]);
        }
        // ---- W frags (pre-split, swizzled); col = wc*64 + n*32 + l31 ----
        bf16x8 wh[2][2], wl[2][2];
        #pragma unroll
        for (int n = 0; n < 2; ++n)
            #pragma unroll
            for (int kh = 0; kh < 2; ++kh) {
                const int off = swz(wc*64 + n*32 + l31, kh*2 + hi);
                wh[n][kh] = *(const bf16x8*)(Whb + off);
                wl[n][kh] = *(const bf16x8*)(Wlb + off);
            }
        #pragma unroll
        for (int kh = 0; kh < 2; ++kh)
            #pragma unroll
            for (int n = 0; n < 2; ++n) {
                acc[n] = __builtin_amdgcn_mfma_f32_32x32x16_bf16(ah[kh].v, wh[n][kh], acc[n], 0,0,0);
                acc[n] = __builtin_amdgcn_mfma_f32_32x32x16_bf16(ah[kh].v, wl[n][kh], acc[n], 0,0,0);
                acc[n] = __builtin_amdgcn_mfma_f32_32x32x16_bf16(al[kh].v, wh[n][kh], acc[n], 0,0,0);
            }
        __syncthreads();
    }
    #undef STAGE

    // ---- epilogues. col = by*128 + wc*64 + n*32 + l31 -> h = by*2+wc, d = n*32+l31.
    //      row(reg) = bx*128 + wr*32 + (reg&3) + 8*(reg>>2) + 4*hi.
    const int h = by*2 + wc;

    if (pid < 2) {      // RoPE (pid0: *QSC -> qb plain; pid1: -> kb tiled)
        unsigned short* Out = pid ? kb : qb;
        const float QSC = pid ? 1.0f : 0.125f * 1.44269504088896340736f;
        const float invf = exp2f((float)l31 * -0.4152410118609203f);
        const float b1 = bias[h*64 + l31], b2 = bias[h*64 + l31 + 32];
        #pragma unroll
        for (int r = 0; r < 16; ++r) {
            const int srow = bx*128 + wr*32 + (r&3) + 8*(r>>2) + 4*hi;
            const int b = srow >> 11, s = srow & 2047;
            float sn, cc;
            __sincosf((float)s * invf, &sn, &cc);
            const float x1 = acc[0][r] + b1;
            const float x2 = acc[1][r] + b2;
            const float o1 = (x1*cc - x2*sn) * QSC;
            const float o2 = (x2*cc + x1*sn) * QSC;
            unsigned short* hb2 = Out + (size_t)(b*H_ + h) * S_ * DK;
            if (pid == 0) {
                unsigned short* dst = hb2 + (size_t)s * DK;
                dst[l31]      = f2bf(o1);
                dst[l31 + 32] = f2bf(o2);
            } else {
                unsigned short* tb = hb2 + (s >> 6) * 4096 + (s & 63) * 8;
                tb[(l31 >> 3) * 512 + (l31 & 7)]          = f2bf(o1);
                tb[((l31 >> 3) + 4) * 512 + (l31 & 7)]    = f2bf(o2);
            }
        }
    } else {            // vt TILED
        const int srow0 = bx*128 + wr*32;
        const int b = srow0 >> 11, s0 = srow0 & 2047;
        unsigned short* tb0 = vt + (size_t)(b*H_ + h) * S_ * DK + (s0 >> 6) * 4096;
        #pragma unroll
        for (int n = 0; n < 2; ++n) {
            const int d = n*32 + l31;
            const float bb = bias[h*64 + d];
            #pragma unroll
            for (int g = 0; g < 4; ++g) {
                u16x4 pk;
                #pragma unroll
                for (int j = 0; j < 4; ++j) pk[j] = f2bf(acc[n][g*4 + j] + bb);
                *(u16x4*)(tb0 + (size_t)((wr&1)*4 + g) * 512 + d*8 + 4*hi) = pk;
            }
        }
    }
}

// ---------------------------------------------------------------------------
// Output-projection split-GEMM, 32x32x16 MFMA (pre-split A via gload).
// ---------------------------------------------------------------------------
__global__ __launch_bounds__(512) void mfma_gemm0(
    const unsigned short* __restrict__ Ah, const unsigned short* __restrict__ Al,
    const unsigned short* __restrict__ Wh, const unsigned short* __restrict__ Wl,
    const float* __restrict__ bias, float* __restrict__ Out)
{
    __shared__ __align__(16) unsigned short lds[2][4][4096];
    const int tid = threadIdx.x;
    const int w = tid >> 6, lane = tid & 63;
    const int l31 = lane & 31, hi = lane >> 5;
    const int wr = w >> 1, wc = w & 1;
    const int bx = blockIdx.x, by = blockIdx.y;

    const int tileId = w >> 1;
    const int halfT  = w & 1;
    const unsigned short* gsrc = (tileId==0) ? Ah : (tileId==1) ? Al : (tileId==2) ? Wh : Wl;
    const int row0 = (tileId < 2) ? bx * 128 : by * 128;
    const int su_   = (lane & 7) ^ (lane >> 3);
    const int wrow_ = halfT * 64 + ((lane >> 3) << 1) + (su_ >> 2);
    const char* gp0 = (const char*)gsrc + (size_t)(row0 + wrow_) * 2048 + (su_ & 3) * 16;

    f32x16 acc[2];
    #pragma unroll
    for (int n = 0; n < 2; ++n)
        #pragma unroll
        for (int r = 0; r < 16; ++r) acc[n][r] = 0.f;

    #define STAGE(T, BUF) do {                                              \
        const char* g_ = gp0 + (size_t)(T) * 64;                            \
        unsigned short* lb_ = &lds[BUF][tileId][halfT * 2048];              \
        gload_lds16(g_,          lb_);                                      \
        gload_lds16(g_ + 32768,  lb_ + 512);                                \
        gload_lds16(g_ + 65536,  lb_ + 1024);                               \
        gload_lds16(g_ + 98304,  lb_ + 1536);                               \
    } while (0)

    STAGE(0, 0);
    __syncthreads();

    for (int t = 0; t < 32; ++t) {
        const int cur = t & 1;
        if (t < 31) STAGE(t + 1, cur ^ 1);
        const unsigned short* lA_h = lds[cur][0];
        const unsigned short* lA_l = lds[cur][1];
        const unsigned short* lW_h = lds[cur][2];
        const unsigned short* lW_l = lds[cur][3];
        bf16x8 ah2[2], al2[2], wh[2][2], wl[2][2];
        #pragma unroll
        for (int kh = 0; kh < 2; ++kh) {
            const int off = swz(wr*32 + l31, kh*2 + hi);
            ah2[kh] = *(const bf16x8*)(lA_h + off);
            al2[kh] = *(const bf16x8*)(lA_l + off);
        }
        #pragma unroll
        for (int n = 0; n < 2; ++n)
            #pragma unroll
            for (int kh = 0; kh < 2; ++kh) {
                const int off = swz(wc*64 + n*32 + l31, kh*2 + hi);
                wh[n][kh] = *(const bf16x8*)(lW_h + off);
                wl[n][kh] = *(const bf16x8*)(lW_l + off);
            }
        #pragma unroll
        for (int kh = 0; kh < 2; ++kh)
            #pragma unroll
            for (int n = 0; n < 2; ++n) {
                acc[n] = __builtin_amdgcn_mfma_f32_32x32x16_bf16(ah2[kh], wh[n][kh], acc[n], 0,0,0);
                acc[n] = __builtin_amdgcn_mfma_f32_32x32x16_bf16(ah2[kh], wl[n][kh], acc[n], 0,0,0);
                acc[n] = __builtin_amdgcn_mfma_f32_32x32x16_bf16(al2[kh], wh[n][kh], acc[n], 0,0,0);
            }
        __syncthreads();
    }
    #undef STAGE

    #pragma unroll
    for (int n = 0; n < 2; ++n) {
        const int col = by*128 + wc*64 + n*32 + l31;
        const float bb = bias[col];
        #pragma unroll
        for (int r = 0; r < 16; ++r) {
            const int row = bx*128 + wr*32 + (r&3) + 8*(r>>2) + 4*hi;
            Out[(size_t)row * 1024 + col] = acc[n][r] + bb;
        }
    }
}

// ---------------------------------------------------------------------------
// 32x32-MFMA flash attention (unchanged — best known).
// ---------------------------------------------------------------------------
__global__ __launch_bounds__(512, 1) void attn_mfma7(
    const unsigned short* __restrict__ Qb, const unsigned short* __restrict__ Kb,
    const unsigned short* __restrict__ Vt,
    unsigned short* __restrict__ Xh, unsigned short* __restrict__ Xl)
{
    __shared__ __align__(16) char lds[65536];
    const unsigned bid = blockIdx.x;             // 256 blocks
    const int xcd = bid & 7, idx = bid >> 3;
    const int bh  = xcd * 4 + (idx >> 3);
    const int qt  = idx & 7;
    const int tid = threadIdx.x;
    const int w = tid >> 6, lane = tid & 63;
    const int l31 = lane & 31, hi = lane >> 5;
    const size_t bhO = (size_t)bh * S_ * DK;
    const int q0 = qt * 256 + w * 32;

    const int u0   = w * 4;
    const int isV  = u0 >> 4;
    const int u15  = u0 & 15;
    const int su0  = u15 >> 3;
    const unsigned short* sb = (isV ? Vt : Kb) + bhO;
    const int ch0 = u15 & 7;
    char* const dbase = lds;

    bf16x8 qf[4];
    #pragma unroll
    for (int ks = 0; ks < 4; ++ks)
        qf[ks] = *(const bf16x8*)(Qb + bhO + (size_t)(q0 + l31) * DK + ks*16 + hi*8);

    f32x16 oT[2];
    #pragma unroll
    for (int dh = 0; dh < 2; ++dh)
        #pragma unroll
        for (int r = 0; r < 16; ++r) oT[dh][r] = 0.f;
    float l_ = 0.f;

    #define ASTAGE(T, BUF) do {                                                     \
        const unsigned short* g_ = sb + (size_t)((T)*2 + su0) * 4096 + ch0 * 512    \
                                   + lane * 8;                                      \
        char* d_ = dbase + (BUF)*32768 + isV*16384 + su0*8192 + ch0*1024 + lane*16; \
        gload_lds16(g_,         d_);                                                \
        gload_lds16(g_ + 512,   d_ + 1024);                                         \
        gload_lds16(g_ + 1024,  d_ + 2048);                                         \
        gload_lds16(g_ + 1536,  d_ + 3072);                                         \
    } while (0)

    ASTAGE(0, 0);
    __syncthreads();

    for (int t = 0; t < 16; ++t) {
        const int cur = t & 1;
        if (t < 15) ASTAGE(t + 1, cur ^ 1);
        const char* Kl = lds + cur * 32768;
        const char* Vl = Kl + 16384;

        f32x16 s2[4];
        __builtin_amdgcn_s_setprio(1);
        #pragma unroll
        for (int kb2 = 0; kb2 < 4; ++kb2) {
            f32x16 a;
            #pragma unroll
            for (int r = 0; r < 16; ++r) a[r] = 0.f;
            const char* kbase = Kl + (kb2 >> 1) * 8192 + ((kb2 & 1) * 32 + l31) * 16;
            #pragma unroll
            for (int ks = 0; ks < 4; ++ks) {
                bf16x8 kf = *(const bf16x8*)(kbase + (ks*2 + hi) * 1024);
                a = __builtin_amdgcn_mfma_f32_32x32x16_bf16(kf, qf[ks], a, 0, 0, 0);
            }
            s2[kb2] = a;
        }
        __builtin_amdgcn_s_setprio(0);

        {
            float lsum = 0.f;
            #pragma unroll
            for (int kb2 = 0; kb2 < 4; ++kb2)
                #pragma unroll
                for (int r = 0; r < 16; ++r) {
                    const float p = EXP2(s2[kb2][r]);
                    s2[kb2][r] = p; lsum += p;
                }
            l_ += lsum;
        }

        // PV: P-frag via cvt_pk + permlane32_swap.
        #pragma unroll
        for (int ks2 = 0; ks2 < 8; ++ks2) {
            const int kb2 = ks2 >> 1;
            const int R0  = (ks2 & 1) * 8;
            unsigned a0 = cvtpk(s2[kb2][R0+0], s2[kb2][R0+1]);
            unsigned a1 = cvtpk(s2[kb2][R0+2], s2[kb2][R0+3]);
            unsigned b0 = cvtpk(s2[kb2][R0+4], s2[kb2][R0+5]);
            unsigned b1 = cvtpk(s2[kb2][R0+6], s2[kb2][R0+7]);
            asm("v_permlane32_swap_b32 %0, %1" : "+v"(a0), "+v"(b0));
            asm("v_permlane32_swap_b32 %0, %1" : "+v"(a1), "+v"(b1));
            union { unsigned u[4]; bf16x8 v; } pf;
            pf.u[0] = a0; pf.u[1] = a1; pf.u[2] = b0; pf.u[3] = b1;
            const char* vbase = Vl + (ks2 >> 2) * 8192 + (((ks2 & 3) * 2) + hi) * 1024;
            __builtin_amdgcn_s_setprio(1);
            #pragma unroll
            for (int dh = 0; dh < 2; ++dh) {
                bf16x8 vf = *(const bf16x8*)(vbase + (dh*32 + l31) * 16);
                oT[dh] = __builtin_amdgcn_mfma_f32_32x32x16_bf16(vf, pf.v, oT[dh], 0, 0, 0);
            }
            __builtin_amdgcn_s_setprio(0);
        }
        __syncthreads();
    }
    #undef ASTAGE

    l_ += __shfl_xor(l_, 32, 64);
    const float inv = 1.0f / l_;
    const int b = bh >> 4, h = bh & 15;
    const int q = q0 + l31;
    unsigned short* xh = Xh + (((size_t)b * S_ + q) * H_ + h) * DK;
    unsigned short* xl = Xl + (((size_t)b * S_ + q) * H_ + h) * DK;
    #pragma unroll
    for (int dh = 0; dh < 2; ++dh)
        #pragma unroll
        for (int tt = 0; tt < 4; ++tt) {
            const int dk0 = dh*32 + tt*8 + hi*4;
            u16x4 hv, lv;
            #pragma unroll
            for (int r = 0; r < 4; ++r) {
                const float o = oT[dh][tt*4 + r] * inv;
                const unsigned short hb = f2bf(o);
                hv[r] = hb;
                lv[r] = f2bf(o - bf2f(hb));
            }
            *(u16x4*)(xh + dk0) = hv;
            *(u16x4*)(xl + dk0) = lv;
        }
}

// ---------------------------------------------------------------------------
extern "C" void kernel_launch(void* const* d_in, const int* in_sizes, int n_in,
                              void* d_out, int out_size, void* d_ws, size_t ws_size,
                              hipStream_t stream)
{
    const float* query = (const float*)d_in[0];
    const float* key   = (const float*)d_in[1];
    const float* value = (const float*)d_in[2];
    const float* Wq = (const float*)d_in[3];  const float* bq = (const float*)d_in[4];
    const float* Wk = (const float*)d_in[5];  const float* bk = (const float*)d_in[6];
    const float* Wv = (const float*)d_in[7];  const float* bv = (const float*)d_in[8];
    const float* Wo = (const float*)d_in[9];  const float* bo = (const float*)d_in[10];
    float* out = (float*)d_out;

    char* ws = (char*)d_ws;
    const size_t MB = (size_t)1 << 20;
    unsigned short* Xh  = (unsigned short*)(ws + 0*MB);
    unsigned short* Xl  = (unsigned short*)(ws + 8*MB);
    unsigned short* qb  = (unsigned short*)(ws + 16*MB);
    unsigned short* vt  = (unsigned short*)(ws + 24*MB);
    unsigned short* kb  = (unsigned short*)(ws + 40*MB);
    unsigned short* wsp = (unsigned short*)(ws + 48*MB);
    unsigned short* Woh = wsp + 6291456;     unsigned short* Wol = wsp + 7340032;

    wsplit4<<<2048, 256, 0, stream>>>(Wq, Wk, Wv, Wo, wsp);

    trigemm<<<dim3(32, 8, 3), 512, 0, stream>>>(query, key, value, wsp,
                                                bq, bk, bv, qb, kb, vt);

    attn_mfma7<<<256, 512, 0, stream>>>(qb, kb, vt, Xh, Xl);

    mfma_gemm0<<<dim3(32, 8), 512, 0, stream>>>(Xh, Xl, Woh, Wol, bo, out);
}

// Round 15
// 150.337 us; speedup vs baseline: 1.1716x; 1.1716x over previous
//
#include <hip/hip_runtime.h>
#include <hip/hip_bf16.h>
#include <math.h>

// B=2, S=2048, D=1024, H=16, dk=64.
// wsplit4 (Wq/Wk/Wv -> fp16 hi only; Wo -> bf16 hi/lo) -> ONE fused tri-GEMM
// (q/k/v; A staged RAW FP32 via global_load_lds, split to fp16 hi/lo in-register;
// 2-term fp16 MFMA C = Ah*Wh + Al*Wh; fused RoPE / tiled-V epilogues)
// -> 32x32-MFMA flash attention (8-wave, KVBLK=128, register softmax,
// permlane32_swap) -> bf16 3-term split-GEMM (output projection).
//
// trigemm LDS per buf (24KB x 2 = 48KB): A fp32 tile 16KB | Wh fp16 8KB.
//  A tile: 128 rows x 32 fp32; 16B chunk (R,c), c=0..7: linear u = R*8 + (c^(R&7)).
//  W tile: [128][32] f16, u16-offset swz(R,c) (superrow XOR).
// All staging via global_load_lds: linear dest + pre-permuted per-lane source.
//
// Tiled K layout per (b,h): 64-key tile t at t*4096 elems; within tile:
//   elem(key r, dk d) at chunk(d>>3)*512 + r*8 + (d&7).
// Tiled V layout per (b,h): 64-key tile t at t*4096; elem(dk dkr, key s):
//   chunk((s&63)>>3)*512 + dkr*8 + (s&7).
//
// ws (64 MB):
//  [0,8) Xh  [8,16) Xl | [16,24) qb | [24,32) vt | [40,48) kb | [48,64) W splits
//  W splits (shorts from ws+48MB): Wq_h16 @0, Wk_h16 @1M, Wv_h16 @2M,
//                                  Wo_bf16hi @3M, Wo_bf16lo @4M.

#define B_ 2
#define S_ 2048
#define D_ 1024
#define H_ 16
#define DK 64

typedef __attribute__((ext_vector_type(8)))  __bf16    bf16x8;
typedef __attribute__((ext_vector_type(8)))  _Float16  f16x8;
typedef __attribute__((ext_vector_type(4)))  float     f32x4;
typedef __attribute__((ext_vector_type(16))) float     f32x16;
typedef __attribute__((ext_vector_type(8)))  unsigned short u16x8;
typedef __attribute__((ext_vector_type(4)))  unsigned short u16x4;

#if __has_builtin(__builtin_amdgcn_exp2f)
#define EXP2(x) __builtin_amdgcn_exp2f(x)
#else
#define EXP2(x) exp2f(x)
#endif

static __device__ __forceinline__ unsigned short f2bf(float x) {
    union { float f; unsigned u; } v; v.f = x;
    unsigned r = v.u + 0x7FFFu + ((v.u >> 16) & 1u);   // RNE
    return (unsigned short)(r >> 16);
}
static __device__ __forceinline__ float bf2f(unsigned short h) {
    union { unsigned u; float f; } v; v.u = ((unsigned)h) << 16;
    return v.f;
}
static __device__ __forceinline__ unsigned cvtpk(float lo, float hi) {
    unsigned r;
    asm("v_cvt_pk_bf16_f32 %0, %1, %2" : "=v"(r) : "v"(lo), "v"(hi));
    return r;
}
static __device__ __forceinline__ unsigned cvtpk16(float lo, float hi) {
    unsigned r;
    asm("v_cvt_pkrtz_f16_f32 %0, %1, %2" : "=v"(r) : "v"(lo), "v"(hi));
    return r;
}
static __device__ __forceinline__ void gload_lds16(const void* g, void* l) {
    __builtin_amdgcn_global_load_lds(
        (const __attribute__((address_space(1))) void*)g,
        (__attribute__((address_space(3))) void*)l, 16, 0, 0);
}
// shorts offset of logical (row R, 8-elem chunk c) in an 8KB [128][32] tile.
static __device__ __forceinline__ int swz(int R, int c) {
    return ((R >> 1) << 6) + (((((R & 1) << 2) | c) ^ ((R >> 1) & 7)) << 3);
}
union bfrag  { unsigned u[4]; bf16x8 v; };
union ffrag  { unsigned u[4]; f16x8  v; };
// bf16 2-fp32 split (RNE, self-correcting) — used for Wo / attn epilogue path.
static __device__ __forceinline__ void splitpk(float e0, float e1,
                                               unsigned& hd, unsigned& ld) {
    hd = cvtpk(e0, e1);
    union { unsigned u; float f; } flo, fhi;
    flo.u = hd << 16; fhi.u = hd & 0xFFFF0000u;
    ld = cvtpk(e0 - flo.f, e1 - fhi.f);
}
// fp16 2-fp32 split (RTZ pack; lo corrects remainder exactly).
static __device__ __forceinline__ void splitpk16(float e0, float e1,
                                                 unsigned& hd, unsigned& ld) {
    hd = cvtpk16(e0, e1);
    union { unsigned u; _Float16 h[2]; } t; t.u = hd;
    ld = cvtpk16(e0 - (float)t.h[0], e1 - (float)t.h[1]);
}

// ---------------------------------------------------------------------------
// Weight splits: t<3 -> fp16 hi only (RNE); t==3 (Wo) -> bf16 hi/lo.
// ---------------------------------------------------------------------------
__global__ __launch_bounds__(256) void wsplit4(
    const float* __restrict__ W0, const float* __restrict__ W1,
    const float* __restrict__ W2, const float* __restrict__ W3,
    unsigned short* __restrict__ out)
{
    const int idx = blockIdx.x * 256 + threadIdx.x;
    const int t = idx >> 17;
    const size_t e = (size_t)(idx & 131071) * 8;
    if (t < 3) {
        const float* src = (t==0 ? W0 : t==1 ? W1 : W2) + e;
        float4 a = *(const float4*)src;
        float4 b = *(const float4*)(src + 4);
        float x[8] = {a.x,a.y,a.z,a.w,b.x,b.y,b.z,b.w};
        union { _Float16 h[8]; u16x8 v; } H;
        #pragma unroll
        for (int j = 0; j < 8; ++j) H.h[j] = (_Float16)x[j];   // RNE
        *(u16x8*)(out + (size_t)t * 1048576 + e) = H.v;
    } else {
        const float* src = W3 + e;
        float4 a = *(const float4*)src;
        float4 b = *(const float4*)(src + 4);
        float x[8] = {a.x,a.y,a.z,a.w,b.x,b.y,b.z,b.w};
        union { unsigned u[4]; u16x8 v; } H, L;
        #pragma unroll
        for (int j = 0; j < 4; ++j) splitpk(x[2*j], x[2*j+1], H.u[j], L.u[j]);
        *(u16x8*)(out + (size_t)3 * 1048576 + e) = H.v;
        *(u16x8*)(out + (size_t)4 * 1048576 + e) = L.v;
    }
}

// ---------------------------------------------------------------------------
// Fused tri-GEMM (blockIdx.z = problem), fp16 2-term: C = Ah*Wh + Al*Wh.
// A staged fp32 via global_load_lds (waves 0-3); Wh fp16 via global_load_lds
// (waves 4-5). A split to fp16 hi/lo in-register. One barrier per K-step.
// pid 0: RoPE*QSC -> qb (B,H,S,dk). pid 1: RoPE -> kb TILED. pid 2: vt TILED.
// ---------------------------------------------------------------------------
__global__ __launch_bounds__(512) void trigemm(
    const float* __restrict__ Aq, const float* __restrict__ Ak,
    const float* __restrict__ Av, const unsigned short* __restrict__ wsp,
    const float* __restrict__ bq, const float* __restrict__ bk,
    const float* __restrict__ bv,
    unsigned short* __restrict__ qb, unsigned short* __restrict__ kb,
    unsigned short* __restrict__ vt)
{
    __shared__ __align__(16) char ldsb[49152];   // 2 bufs x (A 16K | Wh 8K)
    const int pid = blockIdx.z;
    const float* A    = (pid==0) ? Aq : (pid==1) ? Ak : Av;
    const float* bias = (pid==0) ? bq : (pid==1) ? bk : bv;
    const unsigned short* Whp = wsp + (size_t)pid * 1048576;

    const int tid = threadIdx.x;
    const int w = tid >> 6, lane = tid & 63;
    const int l15 = lane & 15, g4 = lane >> 4;
    const int wr = w >> 1, wc = w & 1;
    const int bx = blockIdx.x, by = blockIdx.y;

    // ---- staging geometry (per-lane permuted sources, linear LDS dests) ----
    const int lr8 = lane >> 3;               // 0..7
    const int zz  = (lane & 7) ^ lr8;        // permuted slot
    // A (waves 0-3): lane covers row w*32 + j*8 + lr8, fp32 chunk zz (16B)
    const float* gpA = A + (size_t)(bx*128 + w*32 + lr8) * 1024 + zz * 4;
    // Wh (waves 4-5): qq = w-4 selects 64-row half
    const int qq = w - 4;
    const int wR0 = qq*64 + (lr8 << 1) + (zz >> 2);
    const unsigned short* gpW = Whp + (size_t)(by*128 + wR0) * 1024 + (zz & 3) * 8;

    f32x4 acc[2][4];
    #pragma unroll
    for (int m = 0; m < 2; ++m)
        #pragma unroll
        for (int n = 0; n < 4; ++n) acc[m][n] = (f32x4){0.f,0.f,0.f,0.f};

    #define STAGE(T, BUF) do {                                               \
        if (w < 4) {                                                         \
            const float* g_ = gpA + (size_t)(T) * 32;                        \
            char* d_ = ldsb + (BUF)*24576 + w*4096;                          \
            gload_lds16(g_,          d_);                                    \
            gload_lds16(g_ + 8192,   d_ + 1024);                             \
            gload_lds16(g_ + 16384,  d_ + 2048);                             \
            gload_lds16(g_ + 24576,  d_ + 3072);                             \
        } else if (w < 6) {                                                  \
            const unsigned short* g_ = gpW + (size_t)(T) * 32;               \
            char* d_ = ldsb + (BUF)*24576 + 16384 + qq*4096;                 \
            gload_lds16(g_,          d_);                                    \
            gload_lds16(g_ + 16384,  d_ + 1024);                             \
            gload_lds16(g_ + 32768,  d_ + 2048);                             \
            gload_lds16(g_ + 49152,  d_ + 3072);                             \
        }                                                                    \
    } while (0)

    STAGE(0, 0);
    __syncthreads();

    for (int t = 0; t < 32; ++t) {
        const int cur = t & 1;
        if (t < 31) STAGE(t + 1, cur ^ 1);
        const char* Abuf = ldsb + cur * 24576;
        const unsigned short* Whb = (const unsigned short*)(Abuf + 16384);

        // ---- A frags: read fp32 from LDS, split to fp16 hi/lo in-register ----
        ffrag ah[2], al[2];
        #pragma unroll
        for (int m = 0; m < 2; ++m) {
            const int R = wr*32 + m*16 + l15;
            const int b8 = R * 8, r7 = R & 7;
            f32x4 x0 = *(const f32x4*)(Abuf + (size_t)(b8 + ((g4*2)     ^ r7)) * 16);
            f32x4 x1 = *(const f32x4*)(Abuf + (size_t)(b8 + ((g4*2 + 1) ^ r7)) * 16);
            splitpk16(x0[0], x0[1], ah[m].u[0], al[m].u[0]);
            splitpk16(x0[2], x0[3], ah[m].u[1], al[m].u[1]);
            splitpk16(x1[0], x1[1], ah[m].u[2], al[m].u[2]);
            splitpk16(x1[2], x1[3], ah[m].u[3], al[m].u[3]);
        }
        // ---- W frags (fp16 hi only, swizzled) ----
        f16x8 wh4[4];
        #pragma unroll
        for (int n = 0; n < 4; ++n) {
            const int off = swz(wc*64 + n*16 + l15, g4);
            wh4[n] = *(const f16x8*)(Whb + off);
        }
        #pragma unroll
        for (int m = 0; m < 2; ++m)
            #pragma unroll
            for (int n = 0; n < 4; ++n) {
                acc[m][n] = __builtin_amdgcn_mfma_f32_16x16x32_f16(ah[m].v, wh4[n], acc[m][n], 0,0,0);
                acc[m][n] = __builtin_amdgcn_mfma_f32_16x16x32_f16(al[m].v, wh4[n], acc[m][n], 0,0,0);
            }
        __syncthreads();
    }
    #undef STAGE

    const int colBase = by*128 + wc*64;
    const int rowBase = bx*128 + wr*32;
    const int h = colBase >> 6;

    if (pid < 2) {      // RoPE epilogues (pid0: *QSC -> qb plain; pid1: -> kb tiled)
        unsigned short* Out = pid ? kb : qb;
        const float QSC = pid ? 1.0f : 0.125f * 1.44269504088896340736f;
        #pragma unroll
        for (int m = 0; m < 2; ++m) {
            const int srow0 = rowBase + m*16 + g4*4;
            const int b = srow0 >> 11;
            unsigned short* hb2 = Out + (size_t)(b*H_ + h) * S_ * DK;
            #pragma unroll
            for (int n = 0; n < 2; ++n) {
                const int d = n*16 + l15;
                const float invf = exp2f((float)d * -0.4152410118609203f);
                const float b1 = bias[h*64 + d], b2 = bias[h*64 + d + 32];
                #pragma unroll
                for (int r = 0; r < 4; ++r) {
                    const int s = (srow0 + r) & 2047;
                    const float x1 = acc[m][n][r]   + b1;
                    const float x2 = acc[m][n+2][r] + b2;
                    float sn, cc;
                    __sincosf((float)s * invf, &sn, &cc);
                    const float o1 = (x1*cc - x2*sn) * QSC;
                    const float o2 = (x2*cc + x1*sn) * QSC;
                    if (pid == 0) {
                        unsigned short* dst = hb2 + (size_t)s * DK;
                        dst[d]      = f2bf(o1);
                        dst[d + 32] = f2bf(o2);
                    } else {
                        unsigned short* tb = hb2 + (s >> 6) * 4096 + (s & 63) * 8;
                        tb[(d >> 3) * 512 + (d & 7)]        = f2bf(o1);
                        tb[(d >> 3) * 512 + 2048 + (d & 7)] = f2bf(o2);
                    }
                }
            }
        }
    } else {            // vt TILED
        #pragma unroll
        for (int m = 0; m < 2; ++m) {
            const int srow0 = rowBase + m*16 + g4*4;
            const int b = srow0 >> 11, s0 = srow0 & 2047;
            unsigned short* tb = vt + (size_t)(b*H_ + h) * S_ * DK
                               + (s0 >> 6) * 4096 + ((s0 & 63) >> 3) * 512 + (s0 & 7);
            #pragma unroll
            for (int n = 0; n < 4; ++n) {
                const int d = n*16 + l15;
                const float bb = bias[h*64 + d];
                u16x4 pk;
                #pragma unroll
                for (int r = 0; r < 4; ++r) pk[r] = f2bf(acc[m][n][r] + bb);
                *(u16x4*)(tb + d * 8) = pk;
            }
        }
    }
}

// ---------------------------------------------------------------------------
// Output projection: bf16 3-term split-GEMM (pre-split A via gload). r13 exact.
// ---------------------------------------------------------------------------
__global__ __launch_bounds__(512) void mfma_gemm0(
    const unsigned short* __restrict__ Ah, const unsigned short* __restrict__ Al,
    const unsigned short* __restrict__ Wh, const unsigned short* __restrict__ Wl,
    const float* __restrict__ bias, float* __restrict__ Out)
{
    __shared__ __align__(16) unsigned short lds[2][4][4096];
    const int tid = threadIdx.x;
    const int w = tid >> 6, lane = tid & 63;
    const int l15 = lane & 15, g4 = lane >> 4;
    const int wr = w >> 1, wc = w & 1;
    const int bx = blockIdx.x, by = blockIdx.y;

    const int tileId = w >> 1;
    const int halfT  = w & 1;
    const unsigned short* gsrc = (tileId==0) ? Ah : (tileId==1) ? Al : (tileId==2) ? Wh : Wl;
    const int row0 = (tileId < 2) ? bx * 128 : by * 128;
    const int su_   = (lane & 7) ^ (lane >> 3);
    const int wrow_ = halfT * 64 + ((lane >> 3) << 1) + (su_ >> 2);
    const char* gp0 = (const char*)gsrc + (size_t)(row0 + wrow_) * 2048 + (su_ & 3) * 16;

    f32x4 acc[2][4];
    #pragma unroll
    for (int m = 0; m < 2; ++m)
        #pragma unroll
        for (int n = 0; n < 4; ++n) acc[m][n] = (f32x4){0.f,0.f,0.f,0.f};

    #define STAGE(T, BUF) do {                                              \
        const char* g_ = gp0 + (size_t)(T) * 64;                            \
        unsigned short* lb_ = &lds[BUF][tileId][halfT * 2048];              \
        gload_lds16(g_,          lb_);                                      \
        gload_lds16(g_ + 32768,  lb_ + 512);                                \
        gload_lds16(g_ + 65536,  lb_ + 1024);                               \
        gload_lds16(g_ + 98304,  lb_ + 1536);                               \
    } while (0)

    STAGE(0, 0);
    __syncthreads();

    for (int t = 0; t < 32; ++t) {
        const int cur = t & 1;
        if (t < 31) STAGE(t + 1, cur ^ 1);
        const unsigned short* lA_h = lds[cur][0];
        const unsigned short* lA_l = lds[cur][1];
        const unsigned short* lW_h = lds[cur][2];
        const unsigned short* lW_l = lds[cur][3];
        bf16x8 ah[2], al2[2], wh4[4], wl4[4];
        #pragma unroll
        for (int m = 0; m < 2; ++m) {
            const int off = swz(wr*32 + m*16 + l15, g4);
            ah[m]  = *(const bf16x8*)(lA_h + off);
            al2[m] = *(const bf16x8*)(lA_l + off);
        }
        #pragma unroll
        for (int n = 0; n < 4; ++n) {
            const int off = swz(wc*64 + n*16 + l15, g4);
            wh4[n] = *(const bf16x8*)(lW_h + off);
            wl4[n] = *(const bf16x8*)(lW_l + off);
        }
        #pragma unroll
        for (int m = 0; m < 2; ++m)
            #pragma unroll
            for (int n = 0; n < 4; ++n) {
                acc[m][n] = __builtin_amdgcn_mfma_f32_16x16x32_bf16(ah[m],  wh4[n], acc[m][n], 0,0,0);
                acc[m][n] = __builtin_amdgcn_mfma_f32_16x16x32_bf16(ah[m],  wl4[n], acc[m][n], 0,0,0);
                acc[m][n] = __builtin_amdgcn_mfma_f32_16x16x32_bf16(al2[m], wh4[n], acc[m][n], 0,0,0);
            }
        __syncthreads();
    }
    #undef STAGE

    const int colBase = by*128 + wc*64;
    const int rowBase = bx*128 + wr*32;
    #pragma unroll
    for (int m = 0; m < 2; ++m) {
        const int row = rowBase + m*16 + g4*4;
        #pragma unroll
        for (int n = 0; n < 4; ++n) {
            const int col = colBase + n*16 + l15;
            const float bb = bias[col];
            #pragma unroll
            for (int r = 0; r < 4; ++r)
                Out[(size_t)(row + r) * 1024 + col] = acc[m][n][r] + bb;
        }
    }
}

// ---------------------------------------------------------------------------
// 32x32-MFMA flash attention (r13 exact — best known).
// ---------------------------------------------------------------------------
__global__ __launch_bounds__(512, 1) void attn_mfma7(
    const unsigned short* __restrict__ Qb, const unsigned short* __restrict__ Kb,
    const unsigned short* __restrict__ Vt,
    unsigned short* __restrict__ Xh, unsigned short* __restrict__ Xl)
{
    __shared__ __align__(16) char lds[65536];
    const unsigned bid = blockIdx.x;             // 256 blocks
    const int xcd = bid & 7, idx = bid >> 3;
    const int bh  = xcd * 4 + (idx >> 3);
    const int qt  = idx & 7;
    const int tid = threadIdx.x;
    const int w = tid >> 6, lane = tid & 63;
    const int l31 = lane & 31, hi = lane >> 5;
    const size_t bhO = (size_t)bh * S_ * DK;
    const int q0 = qt * 256 + w * 32;

    const int u0   = w * 4;
    const int isV  = u0 >> 4;
    const int u15  = u0 & 15;
    const int su0  = u15 >> 3;
    const unsigned short* sb = (isV ? Vt : Kb) + bhO;
    const int ch0 = u15 & 7;
    char* const dbase = lds;

    bf16x8 qf[4];
    #pragma unroll
    for (int ks = 0; ks < 4; ++ks)
        qf[ks] = *(const bf16x8*)(Qb + bhO + (size_t)(q0 + l31) * DK + ks*16 + hi*8);

    f32x16 oT[2];
    #pragma unroll
    for (int dh = 0; dh < 2; ++dh)
        #pragma unroll
        for (int r = 0; r < 16; ++r) oT[dh][r] = 0.f;
    float l_ = 0.f;

    #define ASTAGE(T, BUF) do {                                                     \
        const unsigned short* g_ = sb + (size_t)((T)*2 + su0) * 4096 + ch0 * 512    \
                                   + lane * 8;                                      \
        char* d_ = dbase + (BUF)*32768 + isV*16384 + su0*8192 + ch0*1024 + lane*16; \
        gload_lds16(g_,         d_);                                                \
        gload_lds16(g_ + 512,   d_ + 1024);                                         \
        gload_lds16(g_ + 1024,  d_ + 2048);                                         \
        gload_lds16(g_ + 1536,  d_ + 3072);                                         \
    } while (0)

    ASTAGE(0, 0);
    __syncthreads();

    for (int t = 0; t < 16; ++t) {
        const int cur = t & 1;
        if (t < 15) ASTAGE(t + 1, cur ^ 1);
        const char* Kl = lds + cur * 32768;
        const char* Vl = Kl + 16384;

        f32x16 s2[4];
        __builtin_amdgcn_s_setprio(1);
        #pragma unroll
        for (int kb2 = 0; kb2 < 4; ++kb2) {
            f32x16 a;
            #pragma unroll
            for (int r = 0; r < 16; ++r) a[r] = 0.f;
            const char* kbase = Kl + (kb2 >> 1) * 8192 + ((kb2 & 1) * 32 + l31) * 16;
            #pragma unroll
            for (int ks = 0; ks < 4; ++ks) {
                bf16x8 kf = *(const bf16x8*)(kbase + (ks*2 + hi) * 1024);
                a = __builtin_amdgcn_mfma_f32_32x32x16_bf16(kf, qf[ks], a, 0, 0, 0);
            }
            s2[kb2] = a;
        }
        __builtin_amdgcn_s_setprio(0);

        {
            float lsum = 0.f;
            #pragma unroll
            for (int kb2 = 0; kb2 < 4; ++kb2)
                #pragma unroll
                for (int r = 0; r < 16; ++r) {
                    const float p = EXP2(s2[kb2][r]);
                    s2[kb2][r] = p; lsum += p;
                }
            l_ += lsum;
        }

        // PV: P-frag via cvt_pk + permlane32_swap.
        #pragma unroll
        for (int ks2 = 0; ks2 < 8; ++ks2) {
            const int kb2 = ks2 >> 1;
            const int R0  = (ks2 & 1) * 8;
            unsigned a0 = cvtpk(s2[kb2][R0+0], s2[kb2][R0+1]);
            unsigned a1 = cvtpk(s2[kb2][R0+2], s2[kb2][R0+3]);
            unsigned b0 = cvtpk(s2[kb2][R0+4], s2[kb2][R0+5]);
            unsigned b1 = cvtpk(s2[kb2][R0+6], s2[kb2][R0+7]);
            asm("v_permlane32_swap_b32 %0, %1" : "+v"(a0), "+v"(b0));
            asm("v_permlane32_swap_b32 %0, %1" : "+v"(a1), "+v"(b1));
            union { unsigned u[4]; bf16x8 v; } pf;
            pf.u[0] = a0; pf.u[1] = a1; pf.u[2] = b0; pf.u[3] = b1;
            const char* vbase = Vl + (ks2 >> 2) * 8192 + (((ks2 & 3) * 2) + hi) * 1024;
            __builtin_amdgcn_s_setprio(1);
            #pragma unroll
            for (int dh = 0; dh < 2; ++dh) {
                bf16x8 vf = *(const bf16x8*)(vbase + (dh*32 + l31) * 16);
                oT[dh] = __builtin_amdgcn_mfma_f32_32x32x16_bf16(vf, pf.v, oT[dh], 0, 0, 0);
            }
            __builtin_amdgcn_s_setprio(0);
        }
        __syncthreads();
    }
    #undef ASTAGE

    l_ += __shfl_xor(l_, 32, 64);
    const float inv = 1.0f / l_;
    const int b = bh >> 4, h = bh & 15;
    const int q = q0 + l31;
    unsigned short* xh = Xh + (((size_t)b * S_ + q) * H_ + h) * DK;
    unsigned short* xl = Xl + (((size_t)b * S_ + q) * H_ + h) * DK;
    #pragma unroll
    for (int dh = 0; dh < 2; ++dh)
        #pragma unroll
        for (int tt = 0; tt < 4; ++tt) {
            const int dk0 = dh*32 + tt*8 + hi*4;
            u16x4 hv, lv;
            #pragma unroll
            for (int r = 0; r < 4; ++r) {
                const float o = oT[dh][tt*4 + r] * inv;
                const unsigned short hb = f2bf(o);
                hv[r] = hb;
                lv[r] = f2bf(o - bf2f(hb));
            }
            *(u16x4*)(xh + dk0) = hv;
            *(u16x4*)(xl + dk0) = lv;
        }
}

// ---------------------------------------------------------------------------
extern "C" void kernel_launch(void* const* d_in, const int* in_sizes, int n_in,
                              void* d_out, int out_size, void* d_ws, size_t ws_size,
                              hipStream_t stream)
{
    const float* query = (const float*)d_in[0];
    const float* key   = (const float*)d_in[1];
    const float* value = (const float*)d_in[2];
    const float* Wq = (const float*)d_in[3];  const float* bq = (const float*)d_in[4];
    const float* Wk = (const float*)d_in[5];  const float* bk = (const float*)d_in[6];
    const float* Wv = (const float*)d_in[7];  const float* bv = (const float*)d_in[8];
    const float* Wo = (const float*)d_in[9];  const float* bo = (const float*)d_in[10];
    float* out = (float*)d_out;

    char* ws = (char*)d_ws;
    const size_t MB = (size_t)1 << 20;
    unsigned short* Xh  = (unsigned short*)(ws + 0*MB);
    unsigned short* Xl  = (unsigned short*)(ws + 8*MB);
    unsigned short* qb  = (unsigned short*)(ws + 16*MB);
    unsigned short* vt  = (unsigned short*)(ws + 24*MB);
    unsigned short* kb  = (unsigned short*)(ws + 40*MB);
    unsigned short* wsp = (unsigned short*)(ws + 48*MB);
    unsigned short* Woh = wsp + 3145728;     // Wo bf16 hi
    unsigned short* Wol = wsp + 4194304;     // Wo bf16 lo

    wsplit4<<<2048, 256, 0, stream>>>(Wq, Wk, Wv, Wo, wsp);

    trigemm<<<dim3(32, 8, 3), 512, 0, stream>>>(query, key, value, wsp,
                                                bq, bk, bv, qb, kb, vt);

    attn_mfma7<<<256, 512, 0, stream>>>(qb, kb, vt, Xh, Xl);

    mfma_gemm0<<<dim3(32, 8), 512, 0, stream>>>(Xh, Xl, Woh, Wol, bo, out);
}

// Round 16
// 145.680 us; speedup vs baseline: 1.2091x; 1.0320x over previous
//
#include <hip/hip_runtime.h>
#include <hip/hip_bf16.h>
#include <math.h>

// B=2, S=2048, D=1024, H=16, dk=64.
// wsplit4 (Wq/Wk/Wv -> fp16; Wo -> bf16 hi/lo) -> fused tri-GEMM (A fp32 via
// global_load_lds, in-register fp16 hi/lo split, 2-term fp16 MFMA, fused RoPE /
// tiled-V epilogues, COUNTED-VMCNT double-barrier pipeline) -> 32x32-MFMA flash
// attention -> bf16 3-term split-GEMM (same counted-vmcnt pipeline).
//
// Counted-vmcnt discipline (T4/m201): stage(t+1) issues 4 global_load_lds per
// wave; s_waitcnt vmcnt(4) retires tile-t loads while tile-t+1 stays in flight;
// raw s_barrier (NO __syncthreads -> no vmcnt(0) drain). Two barriers/iter:
// data-ready (after vmcnt) and read-done (after compute).
//
// trigemm LDS per buf (24KB x 2): A fp32 16KB | Wh fp16 8KB.
//  A tile: 128 x 32 fp32; 16B chunk (R,c): linear u = R*8 + (c^(R&7)).
//  W tile: [128][32] f16, u16-offset swz(R,c).
// Tiled K per (b,h): tile t at t*4096; elem(key r, dk d) = chunk(d>>3)*512+r*8+(d&7).
// Tiled V per (b,h): tile t at t*4096; elem(dk d, key s) = chunk((s&63)>>3)*512+d*8+(s&7).
//
// ws (64 MB): [0,8) Xh [8,16) Xl | [16,24) qb | [24,32) vt | [40,48) kb |
//  [48,64) W: Wq_f16 @0, Wk_f16 @1M, Wv_f16 @2M, Wo_bf16hi @3M, Wo_bf16lo @4M shorts.

#define B_ 2
#define S_ 2048
#define D_ 1024
#define H_ 16
#define DK 64

typedef __attribute__((ext_vector_type(8)))  __bf16    bf16x8;
typedef __attribute__((ext_vector_type(8)))  _Float16  f16x8;
typedef __attribute__((ext_vector_type(4)))  float     f32x4;
typedef __attribute__((ext_vector_type(16))) float     f32x16;
typedef __attribute__((ext_vector_type(8)))  unsigned short u16x8;
typedef __attribute__((ext_vector_type(4)))  unsigned short u16x4;

#if __has_builtin(__builtin_amdgcn_exp2f)
#define EXP2(x) __builtin_amdgcn_exp2f(x)
#else
#define EXP2(x) exp2f(x)
#endif

static __device__ __forceinline__ unsigned short f2bf(float x) {
    union { float f; unsigned u; } v; v.f = x;
    unsigned r = v.u + 0x7FFFu + ((v.u >> 16) & 1u);   // RNE
    return (unsigned short)(r >> 16);
}
static __device__ __forceinline__ float bf2f(unsigned short h) {
    union { unsigned u; float f; } v; v.u = ((unsigned)h) << 16;
    return v.f;
}
static __device__ __forceinline__ unsigned cvtpk(float lo, float hi) {
    unsigned r;
    asm("v_cvt_pk_bf16_f32 %0, %1, %2" : "=v"(r) : "v"(lo), "v"(hi));
    return r;
}
static __device__ __forceinline__ unsigned cvtpk16(float lo, float hi) {
    unsigned r;
    asm("v_cvt_pkrtz_f16_f32 %0, %1, %2" : "=v"(r) : "v"(lo), "v"(hi));
    return r;
}
static __device__ __forceinline__ void gload_lds16(const void* g, void* l) {
    __builtin_amdgcn_global_load_lds(
        (const __attribute__((address_space(1))) void*)g,
        (__attribute__((address_space(3))) void*)l, 16, 0, 0);
}
static __device__ __forceinline__ int swz(int R, int c) {
    return ((R >> 1) << 6) + (((((R & 1) << 2) | c) ^ ((R >> 1) & 7)) << 3);
}
union bfrag  { unsigned u[4]; bf16x8 v; };
union ffrag  { unsigned u[4]; f16x8  v; };
static __device__ __forceinline__ void splitpk(float e0, float e1,
                                               unsigned& hd, unsigned& ld) {
    hd = cvtpk(e0, e1);
    union { unsigned u; float f; } flo, fhi;
    flo.u = hd << 16; fhi.u = hd & 0xFFFF0000u;
    ld = cvtpk(e0 - flo.f, e1 - fhi.f);
}
static __device__ __forceinline__ void splitpk16(float e0, float e1,
                                                 unsigned& hd, unsigned& ld) {
    hd = cvtpk16(e0, e1);
    union { unsigned u; _Float16 h[2]; } t; t.u = hd;
    ld = cvtpk16(e0 - (float)t.h[0], e1 - (float)t.h[1]);
}

// ---------------------------------------------------------------------------
// Weight splits: t<3 -> fp16 (RNE); t==3 (Wo) -> bf16 hi/lo.
// ---------------------------------------------------------------------------
__global__ __launch_bounds__(256) void wsplit4(
    const float* __restrict__ W0, const float* __restrict__ W1,
    const float* __restrict__ W2, const float* __restrict__ W3,
    unsigned short* __restrict__ out)
{
    const int idx = blockIdx.x * 256 + threadIdx.x;
    const int t = idx >> 17;
    const size_t e = (size_t)(idx & 131071) * 8;
    if (t < 3) {
        const float* src = (t==0 ? W0 : t==1 ? W1 : W2) + e;
        float4 a = *(const float4*)src;
        float4 b = *(const float4*)(src + 4);
        float x[8] = {a.x,a.y,a.z,a.w,b.x,b.y,b.z,b.w};
        union { _Float16 h[8]; u16x8 v; } H;
        #pragma unroll
        for (int j = 0; j < 8; ++j) H.h[j] = (_Float16)x[j];
        *(u16x8*)(out + (size_t)t * 1048576 + e) = H.v;
    } else {
        const float* src = W3 + e;
        float4 a = *(const float4*)src;
        float4 b = *(const float4*)(src + 4);
        float x[8] = {a.x,a.y,a.z,a.w,b.x,b.y,b.z,b.w};
        union { unsigned u[4]; u16x8 v; } H, L;
        #pragma unroll
        for (int j = 0; j < 4; ++j) splitpk(x[2*j], x[2*j+1], H.u[j], L.u[j]);
        *(u16x8*)(out + (size_t)3 * 1048576 + e) = H.v;
        *(u16x8*)(out + (size_t)4 * 1048576 + e) = L.v;
    }
}

// ---------------------------------------------------------------------------
// Fused tri-GEMM, fp16 2-term, counted-vmcnt pipeline.
// ---------------------------------------------------------------------------
__global__ __launch_bounds__(512) void trigemm(
    const float* __restrict__ Aq, const float* __restrict__ Ak,
    const float* __restrict__ Av, const unsigned short* __restrict__ wsp,
    const float* __restrict__ bq, const float* __restrict__ bk,
    const float* __restrict__ bv,
    unsigned short* __restrict__ qb, unsigned short* __restrict__ kb,
    unsigned short* __restrict__ vt)
{
    __shared__ __align__(16) char ldsb[49152];   // 2 bufs x (A 16K | Wh 8K)
    const int pid = blockIdx.z;
    const float* A    = (pid==0) ? Aq : (pid==1) ? Ak : Av;
    const float* bias = (pid==0) ? bq : (pid==1) ? bk : bv;
    const unsigned short* Whp = wsp + (size_t)pid * 1048576;

    const int tid = threadIdx.x;
    const int w = tid >> 6, lane = tid & 63;
    const int l15 = lane & 15, g4 = lane >> 4;
    const int wr = w >> 1, wc = w & 1;
    const int bx = blockIdx.x, by = blockIdx.y;

    const int lr8 = lane >> 3;
    const int zz  = (lane & 7) ^ lr8;
    const float* gpA = A + (size_t)(bx*128 + w*32 + lr8) * 1024 + zz * 4;
    const int qq = w - 4;
    const int wR0 = qq*64 + (lr8 << 1) + (zz >> 2);
    const unsigned short* gpW = Whp + (size_t)(by*128 + wR0) * 1024 + (zz & 3) * 8;

    f32x4 acc[2][4];
    #pragma unroll
    for (int m = 0; m < 2; ++m)
        #pragma unroll
        for (int n = 0; n < 4; ++n) acc[m][n] = (f32x4){0.f,0.f,0.f,0.f};

    #define STAGE(T, BUF) do {                                               \
        if (w < 4) {                                                         \
            const float* g_ = gpA + (size_t)(T) * 32;                        \
            char* d_ = ldsb + (BUF)*24576 + w*4096;                          \
            gload_lds16(g_,          d_);                                    \
            gload_lds16(g_ + 8192,   d_ + 1024);                             \
            gload_lds16(g_ + 16384,  d_ + 2048);                             \
            gload_lds16(g_ + 24576,  d_ + 3072);                             \
        } else if (w < 6) {                                                  \
            const unsigned short* g_ = gpW + (size_t)(T) * 32;               \
            char* d_ = ldsb + (BUF)*24576 + 16384 + qq*4096;                 \
            gload_lds16(g_,          d_);                                    \
            gload_lds16(g_ + 16384,  d_ + 1024);                             \
            gload_lds16(g_ + 32768,  d_ + 2048);                             \
            gload_lds16(g_ + 49152,  d_ + 3072);                             \
        }                                                                    \
    } while (0)

    STAGE(0, 0);
    asm volatile("s_waitcnt vmcnt(0)" ::: "memory");
    __builtin_amdgcn_s_barrier();
    asm volatile("" ::: "memory");

    for (int t = 0; t < 32; ++t) {
        const int cur = t & 1;
        if (t < 31) {
            STAGE(t + 1, cur ^ 1);                       // 4 loads stay in flight
            asm volatile("s_waitcnt vmcnt(4)" ::: "memory");  // tile-t loads retired
        } else {
            asm volatile("s_waitcnt vmcnt(0)" ::: "memory");
        }
        __builtin_amdgcn_s_barrier();                    // all waves: tile-t ready
        asm volatile("" ::: "memory");

        const char* Abuf = ldsb + cur * 24576;
        const unsigned short* Whb = (const unsigned short*)(Abuf + 16384);

        ffrag ah[2], al[2];
        #pragma unroll
        for (int m = 0; m < 2; ++m) {
            const int R = wr*32 + m*16 + l15;
            const int b8 = R * 8, r7 = R & 7;
            f32x4 x0 = *(const f32x4*)(Abuf + (size_t)(b8 + ((g4*2)     ^ r7)) * 16);
            f32x4 x1 = *(const f32x4*)(Abuf + (size_t)(b8 + ((g4*2 + 1) ^ r7)) * 16);
            splitpk16(x0[0], x0[1], ah[m].u[0], al[m].u[0]);
            splitpk16(x0[2], x0[3], ah[m].u[1], al[m].u[1]);
            splitpk16(x1[0], x1[1], ah[m].u[2], al[m].u[2]);
            splitpk16(x1[2], x1[3], ah[m].u[3], al[m].u[3]);
        }
        f16x8 wh4[4];
        #pragma unroll
        for (int n = 0; n < 4; ++n) {
            const int off = swz(wc*64 + n*16 + l15, g4);
            wh4[n] = *(const f16x8*)(Whb + off);
        }
        #pragma unroll
        for (int m = 0; m < 2; ++m)
            #pragma unroll
            for (int n = 0; n < 4; ++n) {
                acc[m][n] = __builtin_amdgcn_mfma_f32_16x16x32_f16(ah[m].v, wh4[n], acc[m][n], 0,0,0);
                acc[m][n] = __builtin_amdgcn_mfma_f32_16x16x32_f16(al[m].v, wh4[n], acc[m][n], 0,0,0);
            }

        asm volatile("" ::: "memory");
        __builtin_amdgcn_s_barrier();                    // all waves: tile-t reads done
        asm volatile("" ::: "memory");
    }
    #undef STAGE

    const int colBase = by*128 + wc*64;
    const int rowBase = bx*128 + wr*32;
    const int h = colBase >> 6;

    if (pid < 2) {
        unsigned short* Out = pid ? kb : qb;
        const float QSC = pid ? 1.0f : 0.125f * 1.44269504088896340736f;
        #pragma unroll
        for (int m = 0; m < 2; ++m) {
            const int srow0 = rowBase + m*16 + g4*4;
            const int b = srow0 >> 11;
            unsigned short* hb2 = Out + (size_t)(b*H_ + h) * S_ * DK;
            #pragma unroll
            for (int n = 0; n < 2; ++n) {
                const int d = n*16 + l15;
                const float invf = exp2f((float)d * -0.4152410118609203f);
                const float b1 = bias[h*64 + d], b2 = bias[h*64 + d + 32];
                #pragma unroll
                for (int r = 0; r < 4; ++r) {
                    const int s = (srow0 + r) & 2047;
                    const float x1 = acc[m][n][r]   + b1;
                    const float x2 = acc[m][n+2][r] + b2;
                    float sn, cc;
                    __sincosf((float)s * invf, &sn, &cc);
                    const float o1 = (x1*cc - x2*sn) * QSC;
                    const float o2 = (x2*cc + x1*sn) * QSC;
                    if (pid == 0) {
                        unsigned short* dst = hb2 + (size_t)s * DK;
                        dst[d]      = f2bf(o1);
                        dst[d + 32] = f2bf(o2);
                    } else {
                        unsigned short* tb = hb2 + (s >> 6) * 4096 + (s & 63) * 8;
                        tb[(d >> 3) * 512 + (d & 7)]        = f2bf(o1);
                        tb[(d >> 3) * 512 + 2048 + (d & 7)] = f2bf(o2);
                    }
                }
            }
        }
    } else {
        #pragma unroll
        for (int m = 0; m < 2; ++m) {
            const int srow0 = rowBase + m*16 + g4*4;
            const int b = srow0 >> 11, s0 = srow0 & 2047;
            unsigned short* tb = vt + (size_t)(b*H_ + h) * S_ * DK
                               + (s0 >> 6) * 4096 + ((s0 & 63) >> 3) * 512 + (s0 & 7);
            #pragma unroll
            for (int n = 0; n < 4; ++n) {
                const int d = n*16 + l15;
                const float bb = bias[h*64 + d];
                u16x4 pk;
                #pragma unroll
                for (int r = 0; r < 4; ++r) pk[r] = f2bf(acc[m][n][r] + bb);
                *(u16x4*)(tb + d * 8) = pk;
            }
        }
    }
}

// ---------------------------------------------------------------------------
// Output projection: bf16 3-term split-GEMM, counted-vmcnt pipeline.
// ---------------------------------------------------------------------------
__global__ __launch_bounds__(512) void mfma_gemm0(
    const unsigned short* __restrict__ Ah, const unsigned short* __restrict__ Al,
    const unsigned short* __restrict__ Wh, const unsigned short* __restrict__ Wl,
    const float* __restrict__ bias, float* __restrict__ Out)
{
    __shared__ __align__(16) unsigned short lds[2][4][4096];
    const int tid = threadIdx.x;
    const int w = tid >> 6, lane = tid & 63;
    const int l15 = lane & 15, g4 = lane >> 4;
    const int wr = w >> 1, wc = w & 1;
    const int bx = blockIdx.x, by = blockIdx.y;

    const int tileId = w >> 1;
    const int halfT  = w & 1;
    const unsigned short* gsrc = (tileId==0) ? Ah : (tileId==1) ? Al : (tileId==2) ? Wh : Wl;
    const int row0 = (tileId < 2) ? bx * 128 : by * 128;
    const int su_   = (lane & 7) ^ (lane >> 3);
    const int wrow_ = halfT * 64 + ((lane >> 3) << 1) + (su_ >> 2);
    const char* gp0 = (const char*)gsrc + (size_t)(row0 + wrow_) * 2048 + (su_ & 3) * 16;

    f32x4 acc[2][4];
    #pragma unroll
    for (int m = 0; m < 2; ++m)
        #pragma unroll
        for (int n = 0; n < 4; ++n) acc[m][n] = (f32x4){0.f,0.f,0.f,0.f};

    #define STAGE(T, BUF) do {                                              \
        const char* g_ = gp0 + (size_t)(T) * 64;                            \
        unsigned short* lb_ = &lds[BUF][tileId][halfT * 2048];              \
        gload_lds16(g_,          lb_);                                      \
        gload_lds16(g_ + 32768,  lb_ + 512);                                \
        gload_lds16(g_ + 65536,  lb_ + 1024);                               \
        gload_lds16(g_ + 98304,  lb_ + 1536);                               \
    } while (0)

    STAGE(0, 0);
    asm volatile("s_waitcnt vmcnt(0)" ::: "memory");
    __builtin_amdgcn_s_barrier();
    asm volatile("" ::: "memory");

    for (int t = 0; t < 32; ++t) {
        const int cur = t & 1;
        if (t < 31) {
            STAGE(t + 1, cur ^ 1);
            asm volatile("s_waitcnt vmcnt(4)" ::: "memory");
        } else {
            asm volatile("s_waitcnt vmcnt(0)" ::: "memory");
        }
        __builtin_amdgcn_s_barrier();
        asm volatile("" ::: "memory");

        const unsigned short* lA_h = lds[cur][0];
        const unsigned short* lA_l = lds[cur][1];
        const unsigned short* lW_h = lds[cur][2];
        const unsigned short* lW_l = lds[cur][3];
        bf16x8 ah[2], al2[2], wh4[4], wl4[4];
        #pragma unroll
        for (int m = 0; m < 2; ++m) {
            const int off = swz(wr*32 + m*16 + l15, g4);
            ah[m]  = *(const bf16x8*)(lA_h + off);
            al2[m] = *(const bf16x8*)(lA_l + off);
        }
        #pragma unroll
        for (int n = 0; n < 4; ++n) {
            const int off = swz(wc*64 + n*16 + l15, g4);
            wh4[n] = *(const bf16x8*)(lW_h + off);
            wl4[n] = *(const bf16x8*)(lW_l + off);
        }
        #pragma unroll
        for (int m = 0; m < 2; ++m)
            #pragma unroll
            for (int n = 0; n < 4; ++n) {
                acc[m][n] = __builtin_amdgcn_mfma_f32_16x16x32_bf16(ah[m],  wh4[n], acc[m][n], 0,0,0);
                acc[m][n] = __builtin_amdgcn_mfma_f32_16x16x32_bf16(ah[m],  wl4[n], acc[m][n], 0,0,0);
                acc[m][n] = __builtin_amdgcn_mfma_f32_16x16x32_bf16(al2[m], wh4[n], acc[m][n], 0,0,0);
            }

        asm volatile("" ::: "memory");
        __builtin_amdgcn_s_barrier();
        asm volatile("" ::: "memory");
    }
    #undef STAGE

    const int colBase = by*128 + wc*64;
    const int rowBase = bx*128 + wr*32;
    #pragma unroll
    for (int m = 0; m < 2; ++m) {
        const int row = rowBase + m*16 + g4*4;
        #pragma unroll
        for (int n = 0; n < 4; ++n) {
            const int col = colBase + n*16 + l15;
            const float bb = bias[col];
            #pragma unroll
            for (int r = 0; r < 4; ++r)
                Out[(size_t)(row + r) * 1024 + col] = acc[m][n][r] + bb;
        }
    }
}

// ---------------------------------------------------------------------------
// 32x32-MFMA flash attention (unchanged — best known).
// ---------------------------------------------------------------------------
__global__ __launch_bounds__(512, 1) void attn_mfma7(
    const unsigned short* __restrict__ Qb, const unsigned short* __restrict__ Kb,
    const unsigned short* __restrict__ Vt,
    unsigned short* __restrict__ Xh, unsigned short* __restrict__ Xl)
{
    __shared__ __align__(16) char lds[65536];
    const unsigned bid = blockIdx.x;
    const int xcd = bid & 7, idx = bid >> 3;
    const int bh  = xcd * 4 + (idx >> 3);
    const int qt  = idx & 7;
    const int tid = threadIdx.x;
    const int w = tid >> 6, lane = tid & 63;
    const int l31 = lane & 31, hi = lane >> 5;
    const size_t bhO = (size_t)bh * S_ * DK;
    const int q0 = qt * 256 + w * 32;

    const int u0   = w * 4;
    const int isV  = u0 >> 4;
    const int u15  = u0 & 15;
    const int su0  = u15 >> 3;
    const unsigned short* sb = (isV ? Vt : Kb) + bhO;
    const int ch0 = u15 & 7;
    char* const dbase = lds;

    bf16x8 qf[4];
    #pragma unroll
    for (int ks = 0; ks < 4; ++ks)
        qf[ks] = *(const bf16x8*)(Qb + bhO + (size_t)(q0 + l31) * DK + ks*16 + hi*8);

    f32x16 oT[2];
    #pragma unroll
    for (int dh = 0; dh < 2; ++dh)
        #pragma unroll
        for (int r = 0; r < 16; ++r) oT[dh][r] = 0.f;
    float l_ = 0.f;

    #define ASTAGE(T, BUF) do {                                                     \
        const unsigned short* g_ = sb + (size_t)((T)*2 + su0) * 4096 + ch0 * 512    \
                                   + lane * 8;                                      \
        char* d_ = dbase + (BUF)*32768 + isV*16384 + su0*8192 + ch0*1024 + lane*16; \
        gload_lds16(g_,         d_);                                                \
        gload_lds16(g_ + 512,   d_ + 1024);                                         \
        gload_lds16(g_ + 1024,  d_ + 2048);                                         \
        gload_lds16(g_ + 1536,  d_ + 3072);                                         \
    } while (0)

    ASTAGE(0, 0);
    __syncthreads();

    for (int t = 0; t < 16; ++t) {
        const int cur = t & 1;
        if (t < 15) ASTAGE(t + 1, cur ^ 1);
        const char* Kl = lds + cur * 32768;
        const char* Vl = Kl + 16384;

        f32x16 s2[4];
        __builtin_amdgcn_s_setprio(1);
        #pragma unroll
        for (int kb2 = 0; kb2 < 4; ++kb2) {
            f32x16 a;
            #pragma unroll
            for (int r = 0; r < 16; ++r) a[r] = 0.f;
            const char* kbase = Kl + (kb2 >> 1) * 8192 + ((kb2 & 1) * 32 + l31) * 16;
            #pragma unroll
            for (int ks = 0; ks < 4; ++ks) {
                bf16x8 kf = *(const bf16x8*)(kbase + (ks*2 + hi) * 1024);
                a = __builtin_amdgcn_mfma_f32_32x32x16_bf16(kf, qf[ks], a, 0, 0, 0);
            }
            s2[kb2] = a;
        }
        __builtin_amdgcn_s_setprio(0);

        {
            float lsum = 0.f;
            #pragma unroll
            for (int kb2 = 0; kb2 < 4; ++kb2)
                #pragma unroll
                for (int r = 0; r < 16; ++r) {
                    const float p = EXP2(s2[kb2][r]);
                    s2[kb2][r] = p; lsum += p;
                }
            l_ += lsum;
        }

        #pragma unroll
        for (int ks2 = 0; ks2 < 8; ++ks2) {
            const int kb2 = ks2 >> 1;
            const int R0  = (ks2 & 1) * 8;
            unsigned a0 = cvtpk(s2[kb2][R0+0], s2[kb2][R0+1]);
            unsigned a1 = cvtpk(s2[kb2][R0+2], s2[kb2][R0+3]);
            unsigned b0 = cvtpk(s2[kb2][R0+4], s2[kb2][R0+5]);
            unsigned b1 = cvtpk(s2[kb2][R0+6], s2[kb2][R0+7]);
            asm("v_permlane32_swap_b32 %0, %1" : "+v"(a0), "+v"(b0));
            asm("v_permlane32_swap_b32 %0, %1" : "+v"(a1), "+v"(b1));
            union { unsigned u[4]; bf16x8 v; } pf;
            pf.u[0] = a0; pf.u[1] = a1; pf.u[2] = b0; pf.u[3] = b1;
            const char* vbase = Vl + (ks2 >> 2) * 8192 + (((ks2 & 3) * 2) + hi) * 1024;
            __builtin_amdgcn_s_setprio(1);
            #pragma unroll
            for (int dh = 0; dh < 2; ++dh) {
                bf16x8 vf = *(const bf16x8*)(vbase + (dh*32 + l31) * 16);
                oT[dh] = __builtin_amdgcn_mfma_f32_32x32x16_bf16(vf, pf.v, oT[dh], 0, 0, 0);
            }
            __builtin_amdgcn_s_setprio(0);
        }
        __syncthreads();
    }
    #undef ASTAGE

    l_ += __shfl_xor(l_, 32, 64);
    const float inv = 1.0f / l_;
    const int b = bh >> 4, h = bh & 15;
    const int q = q0 + l31;
    unsigned short* xh = Xh + (((size_t)b * S_ + q) * H_ + h) * DK;
    unsigned short* xl = Xl + (((size_t)b * S_ + q) * H_ + h) * DK;
    #pragma unroll
    for (int dh = 0; dh < 2; ++dh)
        #pragma unroll
        for (int tt = 0; tt < 4; ++tt) {
            const int dk0 = dh*32 + tt*8 + hi*4;
            u16x4 hv, lv;
            #pragma unroll
            for (int r = 0; r < 4; ++r) {
                const float o = oT[dh][tt*4 + r] * inv;
                const unsigned short hb = f2bf(o);
                hv[r] = hb;
                lv[r] = f2bf(o - bf2f(hb));
            }
            *(u16x4*)(xh + dk0) = hv;
            *(u16x4*)(xl + dk0) = lv;
        }
}

// ---------------------------------------------------------------------------
extern "C" void kernel_launch(void* const* d_in, const int* in_sizes, int n_in,
                              void* d_out, int out_size, void* d_ws, size_t ws_size,
                              hipStream_t stream)
{
    const float* query = (const float*)d_in[0];
    const float* key   = (const float*)d_in[1];
    const float* value = (const float*)d_in[2];
    const float* Wq = (const float*)d_in[3];  const float* bq = (const float*)d_in[4];
    const float* Wk = (const float*)d_in[5];  const float* bk = (const float*)d_in[6];
    const float* Wv = (const float*)d_in[7];  const float* bv = (const float*)d_in[8];
    const float* Wo = (const float*)d_in[9];  const float* bo = (const float*)d_in[10];
    float* out = (float*)d_out;

    char* ws = (char*)d_ws;
    const size_t MB = (size_t)1 << 20;
    unsigned short* Xh  = (unsigned short*)(ws + 0*MB);
    unsigned short* Xl  = (unsigned short*)(ws + 8*MB);
    unsigned short* qb  = (unsigned short*)(ws + 16*MB);
    unsigned short* vt  = (unsigned short*)(ws + 24*MB);
    unsigned short* kb  = (unsigned short*)(ws + 40*MB);
    unsigned short* wsp = (unsigned short*)(ws + 48*MB);
    unsigned short* Woh = wsp + 3145728;     // Wo bf16 hi
    unsigned short* Wol = wsp + 4194304;     // Wo bf16 lo

    wsplit4<<<2048, 256, 0, stream>>>(Wq, Wk, Wv, Wo, wsp);

    trigemm<<<dim3(32, 8, 3), 512, 0, stream>>>(query, key, value, wsp,
                                                bq, bk, bv, qb, kb, vt);

    attn_mfma7<<<256, 512, 0, stream>>>(qb, kb, vt, Xh, Xl);

    mfma_gemm0<<<dim3(32, 8), 512, 0, stream>>>(Xh, Xl, Woh, Wol, bo, out);
}